// Round 5
// baseline (143.448 us; speedup 1.0000x reference)
//
#include <hip/hip_runtime.h>
#include <math.h>

// GAT_28295244546247 — algebraic collapse + full fusion:
//   softmax_j(s_i[i]+s_j[j]+ab) == softmax_j(s_j[j])   (shift invariance over j)
//   => attention rows identical => layer-2 softmax uniform => a1_b/a2_* unused.
//   final[i,:] = leaky( elu(leaky( mean_h (Σ_j e^{s_j} e1[j,:]) / (Σ_j e^{s_j}) )) @ W2^T + b2 )
// Scores are bounded (|s|~4) so exp needs no max-subtraction => plain j-reductions.
// Two-phase deterministic reduce (no atomics, no memset node):
//   k_fused : 256 blocks × 16 rows -> per-block partials pw[b][520]
//   k_final : redundant 256-way reduce (L2) + activations + broadcast write
// R4 bugfix: reduce segments only covered p=0..511; denominators p=512..519
// were never reduced and red[512..] read uninitialized LDS -> absmax 2.4e5.

#define NN 4096
#define FH 64
#define FO 32
#define NH 8
#define RPB 16              // rows per block
#define NB  (NN / RPB)      // 256 blocks
#define NP  (NH * FH + NH)  // 520 partials per block (512 v1 + 8 denom)

__global__ __launch_bounds__(256) void k_fused(const float* __restrict__ x,
    const float* __restrict__ W1, const float* __restrict__ b1,
    const float* __restrict__ a1w, float* __restrict__ pw)
{
    __shared__ float xs[RPB][64];       // staged x rows
    __shared__ float w1t[64 * 65];      // W1 transposed, +1 pad (2-way max = free)
    __shared__ float ps[4][NH][64];     // per-wave partial v1
    __shared__ float ds[4][NH];         // per-wave partial denom

    const int t    = threadIdx.x;
    const int lane = t & 63;
    const int sub  = t >> 6;            // wave id
    const int j0   = blockIdx.x * RPB;

    // stage x rows, coalesced float4
    reinterpret_cast<float4*>(&xs[0][0])[t] =
        reinterpret_cast<const float4*>(x + j0 * 64)[t];

    // stage W1 transposed: w1t[k][f]
    #pragma unroll
    for (int i = t; i < 1024; i += 256) {
        float4 v = reinterpret_cast<const float4*>(W1)[i];
        const int f0 = i >> 4;
        const int k0 = (4 * i) & 63;
        w1t[(k0 + 0) * 65 + f0] = v.x;
        w1t[(k0 + 1) * 65 + f0] = v.y;
        w1t[(k0 + 2) * 65 + f0] = v.z;
        w1t[(k0 + 3) * 65 + f0] = v.w;
    }

    const float bb = b1[lane];
    float ar[NH];
    #pragma unroll
    for (int h = 0; h < NH; ++h) ar[h] = a1w[h * 128 + 64 + lane];

    __syncthreads();

    float part[NH], dsum[NH];
    #pragma unroll
    for (int h = 0; h < NH; ++h) { part[h] = 0.f; dsum[h] = 0.f; }

    #pragma unroll
    for (int r = 0; r < RPB / 4; ++r) {             // 4 rows per wave
        const int row = sub * (RPB / 4) + r;
        float e = bb;                               // e1[j0+row, lane]
        #pragma unroll
        for (int k = 0; k < 64; ++k)
            e = fmaf(xs[row][k], w1t[k * 65 + lane], e);

        #pragma unroll
        for (int h = 0; h < NH; ++h) {
            float p = e * ar[h];
            #pragma unroll
            for (int off = 32; off; off >>= 1) p += __shfl_xor(p, off);
            const float w = __expf(p);              // same in all lanes
            dsum[h] += w;
            part[h]  = fmaf(w, e, part[h]);
        }
    }

    #pragma unroll
    for (int h = 0; h < NH; ++h) ps[sub][h][lane] = part[h];
    if (lane == 0) {
        #pragma unroll
        for (int h = 0; h < NH; ++h) ds[sub][h] = dsum[h];
    }
    __syncthreads();

    // cross-wave reduce -> coalesced per-block partial row pw[b][0..519]
    float* prow = pw + blockIdx.x * NP;
    #pragma unroll
    for (int p = t; p < NH * 64; p += 256)
        prow[p] = ps[0][0][p] + ps[1][0][p] + ps[2][0][p] + ps[3][0][p];
    if (t < NH)
        prow[512 + t] = ds[0][t] + ds[1][t] + ds[2][t] + ds[3][t];
}

// Redundant 256-way reduce of pw (L2-resident), then activations + broadcast.
__global__ __launch_bounds__(256) void k_final(const float* __restrict__ pw,
    const float* __restrict__ W2, const float* __restrict__ b2,
    float* __restrict__ out)
{
    __shared__ float red[NP];
    __shared__ float row1[64];
    __shared__ float fin[FO];
    const int t = threadIdx.x;

    // reduce over 256 blocks; three segments cover all 520 partials:
    //   p = t (0..255), p = 256+t (256..511), p = 512+t for t<8 (denoms)
    float a0 = 0.f, a1 = 0.f, a2 = 0.f;
    #pragma unroll 4
    for (int b = 0; b < NB; ++b) {
        const float* prow = pw + b * NP;
        a0 += prow[t];
        a1 += prow[256 + t];
        if (t < NP - 512) a2 += prow[512 + t];
    }
    red[t] = a0;
    red[256 + t] = a1;
    if (t < NP - 512) red[512 + t] = a2;
    __syncthreads();

    if (t < 64) {
        float m = 0.f;
        #pragma unroll
        for (int h = 0; h < NH; ++h)
            m = fmaf(red[h * 64 + t], 0.125f / red[512 + h], m);
        m = m > 0.f ? m : 0.2f * m;                 // leaky_relu(0.2)
        m = m > 0.f ? m : expm1f(m);                // elu
        row1[t] = m;
    }
    __syncthreads();
    if (t < FO) {
        float acc = b2[t];
        #pragma unroll
        for (int f = 0; f < 64; ++f) acc = fmaf(row1[f], W2[t * 64 + f], acc);
        fin[t] = acc > 0.f ? acc : 0.2f * acc;
    }
    __syncthreads();

    // broadcast: 64 blocks × 2 float4/thread = 32768 float4 = 4096x32 floats
    const int idx0 = blockIdx.x * 512 + t;
    #pragma unroll
    for (int u = 0; u < 2; ++u) {
        const int idx = idx0 + u * 256;
        const int o4  = idx & 7;
        float4 val;
        val.x = fin[o4 * 4 + 0];
        val.y = fin[o4 * 4 + 1];
        val.z = fin[o4 * 4 + 2];
        val.w = fin[o4 * 4 + 3];
        reinterpret_cast<float4*>(out)[idx] = val;
    }
}

extern "C" void kernel_launch(void* const* d_in, const int* in_sizes, int n_in,
                              void* d_out, int out_size, void* d_ws, size_t ws_size,
                              hipStream_t stream) {
    const float* x   = (const float*)d_in[0];
    const float* W1  = (const float*)d_in[1];
    const float* b1  = (const float*)d_in[2];
    const float* a1w = (const float*)d_in[3];
    // d_in[4] a1_b: cancels in softmax.  d_in[7..8] a2_*: layer-2 softmax uniform.
    const float* W2  = (const float*)d_in[5];
    const float* b2  = (const float*)d_in[6];
    float* out = (float*)d_out;

    float* pw = (float*)d_ws;            // [256][520] per-block partials

    k_fused<<<NB, 256, 0, stream>>>(x, W1, b1, a1w, pw);
    k_final<<<64, 256, 0, stream>>>(pw, W2, b2, out);
}

// Round 6
// 83.967 us; speedup vs baseline: 1.7084x; 1.7084x over previous
//
#include <hip/hip_runtime.h>
#include <math.h>

// GAT_28295244546247 — algebraic collapse + full fusion:
//   softmax_j(s_i[i]+s_j[j]+ab) == softmax_j(s_j[j])   (shift invariance over j)
//   => attention rows identical => layer-2 softmax uniform => a1_b/a2_* unused.
//   final[i,:] = leaky( elu(leaky( mean_h (Σ_j e^{s_j} e1[j,:]) / (Σ_j e^{s_j}) )) @ W2^T + b2 )
// Scores are bounded (|s|~4) so exp needs no max-subtraction => plain j-reductions.
//
// R5 post-mortem: deterministic redundant reduce in k_final was a 70 µs
// serial-latency chain (VALUBusy 0.4%, occupancy 2.6%). Reverting to the R2
// structure: fire-and-forget atomicAdd into 520 accumulators (error ~1e-6 <<
// 6.9e-3 threshold; R2 benched absmax 0.0) + tiny memset node. R2 measured
// 83 µs total, dominated by harness 256 MB ws poison fills (~40 µs @ 85% HBM).

#define NN 4096
#define FH 64
#define FO 32
#define NH 8
#define RPB 16              // rows per block
#define NB  (NN / RPB)      // 256 blocks

__global__ __launch_bounds__(256) void k_fused(const float* __restrict__ x,
    const float* __restrict__ W1, const float* __restrict__ b1,
    const float* __restrict__ a1w,
    float* __restrict__ v1, float* __restrict__ dn)
{
    __shared__ float xs[RPB][64];       // staged x rows
    __shared__ float w1t[64 * 65];      // W1 transposed, +1 pad (2-way max = free)
    __shared__ float ps[4][NH][64];     // per-wave partial v1
    __shared__ float ds[4][NH];         // per-wave partial denom

    const int t    = threadIdx.x;
    const int lane = t & 63;
    const int sub  = t >> 6;            // wave id
    const int j0   = blockIdx.x * RPB;

    // stage x rows, coalesced float4
    reinterpret_cast<float4*>(&xs[0][0])[t] =
        reinterpret_cast<const float4*>(x + j0 * 64)[t];

    // stage W1 transposed: w1t[k][f]
    #pragma unroll
    for (int i = t; i < 1024; i += 256) {
        float4 v = reinterpret_cast<const float4*>(W1)[i];
        const int f0 = i >> 4;
        const int k0 = (4 * i) & 63;
        w1t[(k0 + 0) * 65 + f0] = v.x;
        w1t[(k0 + 1) * 65 + f0] = v.y;
        w1t[(k0 + 2) * 65 + f0] = v.z;
        w1t[(k0 + 3) * 65 + f0] = v.w;
    }

    const float bb = b1[lane];
    float ar[NH];
    #pragma unroll
    for (int h = 0; h < NH; ++h) ar[h] = a1w[h * 128 + 64 + lane];

    __syncthreads();

    float part[NH], dsum[NH];
    #pragma unroll
    for (int h = 0; h < NH; ++h) { part[h] = 0.f; dsum[h] = 0.f; }

    #pragma unroll
    for (int r = 0; r < RPB / 4; ++r) {             // 4 rows per wave
        const int row = sub * (RPB / 4) + r;
        float e = bb;                               // e1[j0+row, lane]
        #pragma unroll
        for (int k = 0; k < 64; ++k)
            e = fmaf(xs[row][k], w1t[k * 65 + lane], e);

        #pragma unroll
        for (int h = 0; h < NH; ++h) {
            float p = e * ar[h];
            #pragma unroll
            for (int off = 32; off; off >>= 1) p += __shfl_xor(p, off);
            const float w = __expf(p);              // same in all lanes
            dsum[h] += w;
            part[h]  = fmaf(w, e, part[h]);
        }
    }

    #pragma unroll
    for (int h = 0; h < NH; ++h) ps[sub][h][lane] = part[h];
    if (lane == 0) {
        #pragma unroll
        for (int h = 0; h < NH; ++h) ds[sub][h] = dsum[h];
    }
    __syncthreads();

    // cross-wave reduce + global atomic accumulate (fire-and-forget)
    #pragma unroll
    for (int p = t; p < NH * 64; p += 256) {
        float s = ps[0][0][p] + ps[1][0][p] + ps[2][0][p] + ps[3][0][p];
        atomicAdd(&v1[p], s);
    }
    if (t < NH)
        atomicAdd(&dn[t], ds[0][t] + ds[1][t] + ds[2][t] + ds[3][t]);
}

// row1 = elu(leaky(mean_h v1[h,:]/dn[h])); fin = leaky(row1@W2^T+b2); broadcast.
__global__ __launch_bounds__(256) void k_final(const float* __restrict__ v1,
    const float* __restrict__ dn,
    const float* __restrict__ W2, const float* __restrict__ b2,
    float* __restrict__ out)
{
    __shared__ float invd[NH];
    __shared__ float row1[64];
    __shared__ float fin[FO];
    const int t = threadIdx.x;

    if (t < NH) invd[t] = 0.125f / dn[t];           // fold mean-over-heads
    __syncthreads();
    if (t < 64) {
        float m = 0.f;
        #pragma unroll
        for (int h = 0; h < NH; ++h) m = fmaf(v1[h * 64 + t], invd[h], m);
        m = m > 0.f ? m : 0.2f * m;                 // leaky_relu(0.2)
        m = m > 0.f ? m : expm1f(m);                // elu
        row1[t] = m;
    }
    __syncthreads();
    if (t < FO) {
        float acc = b2[t];
        #pragma unroll
        for (int f = 0; f < 64; ++f) acc = fmaf(row1[f], W2[t * 64 + f], acc);
        fin[t] = acc > 0.f ? acc : 0.2f * acc;
    }
    __syncthreads();

    // broadcast: 64 blocks × 2 float4/thread = 32768 float4 = 4096x32 floats
    const int idx0 = blockIdx.x * 512 + t;
    #pragma unroll
    for (int u = 0; u < 2; ++u) {
        const int idx = idx0 + u * 256;
        const int o4  = idx & 7;
        float4 val;
        val.x = fin[o4 * 4 + 0];
        val.y = fin[o4 * 4 + 1];
        val.z = fin[o4 * 4 + 2];
        val.w = fin[o4 * 4 + 3];
        reinterpret_cast<float4*>(out)[idx] = val;
    }
}

extern "C" void kernel_launch(void* const* d_in, const int* in_sizes, int n_in,
                              void* d_out, int out_size, void* d_ws, size_t ws_size,
                              hipStream_t stream) {
    const float* x   = (const float*)d_in[0];
    const float* W1  = (const float*)d_in[1];
    const float* b1  = (const float*)d_in[2];
    const float* a1w = (const float*)d_in[3];
    // d_in[4] a1_b: cancels in softmax.  d_in[7..8] a2_*: layer-2 softmax uniform.
    const float* W2  = (const float*)d_in[5];
    const float* b2  = (const float*)d_in[6];
    float* out = (float*)d_out;

    float* v1 = (float*)d_ws;            // [8*64] raw weighted sums
    float* dn = v1 + NH * 64;            // [8]    raw denominators

    hipMemsetAsync(v1, 0, (NH * 64 + NH) * sizeof(float), stream);
    k_fused<<<NB, 256, 0, stream>>>(x, W1, b1, a1w, v1, dn);
    k_final<<<64, 256, 0, stream>>>(v1, dn, W2, b2, out);
}